// Round 6
// baseline (599.665 us; speedup 1.0000x reference)
//
#include <hip/hip_runtime.h>
#include <hip/hip_bf16.h>

typedef __attribute__((ext_vector_type(4))) float f32x4;
typedef __attribute__((ext_vector_type(8))) short bf16x8;

#define C_DIM 512
#define SCALE 1.6487212707001282f            // exp(0.5)
#define S2LOG (SCALE * 1.4426950408889634f)  // exp(0.5) * log2(e)
#define NT 8                                  // C_DIM / 64 K-tiles

// -------- Kernel A: L2-normalize rows of pred/target -> bf16; exact fp32 diag; zero sumexp
__global__ __launch_bounds__(128) void cossim_normalize(
    const float* __restrict__ pred, const float* __restrict__ target,
    __hip_bfloat16* __restrict__ pbf, __hip_bfloat16* __restrict__ tbf,
    float* __restrict__ diag, float* __restrict__ sumexp) {
  const int n = blockIdx.x;
  const int t = threadIdx.x;  // 128 threads, 4 floats each = 512
  const float4* p4 = (const float4*)(pred + (size_t)n * C_DIM);
  const float4* q4 = (const float4*)(target + (size_t)n * C_DIM);
  float4 a = p4[t];
  float4 b = q4[t];
  float ssp = a.x*a.x + a.y*a.y + a.z*a.z + a.w*a.w;
  float sst = b.x*b.x + b.y*b.y + b.z*b.z + b.w*b.w;
  float dt  = a.x*b.x + a.y*b.y + a.z*b.z + a.w*b.w;
  #pragma unroll
  for (int off = 32; off > 0; off >>= 1) {
    ssp += __shfl_down(ssp, off);
    sst += __shfl_down(sst, off);
    dt  += __shfl_down(dt,  off);
  }
  __shared__ float red[3][2];
  const int wid = t >> 6;
  if ((t & 63) == 0) { red[0][wid] = ssp; red[1][wid] = sst; red[2][wid] = dt; }
  __syncthreads();
  const float tp = red[0][0] + red[0][1];
  const float tt = red[1][0] + red[1][1];
  const float td = red[2][0] + red[2][1];
  const float rnp = 1.0f / fmaxf(sqrtf(tp), 1e-12f);
  const float rnt = 1.0f / fmaxf(sqrtf(tt), 1e-12f);

  __hip_bfloat16 po[4], to[4];
  po[0] = __float2bfloat16(a.x * rnp); po[1] = __float2bfloat16(a.y * rnp);
  po[2] = __float2bfloat16(a.z * rnp); po[3] = __float2bfloat16(a.w * rnp);
  to[0] = __float2bfloat16(b.x * rnt); to[1] = __float2bfloat16(b.y * rnt);
  to[2] = __float2bfloat16(b.z * rnt); to[3] = __float2bfloat16(b.w * rnt);
  *(uint2*)(pbf + (size_t)n * C_DIM + t * 4) = *(const uint2*)po;
  *(uint2*)(tbf + (size_t)n * C_DIM + t * 4) = *(const uint2*)to;

  if (t == 0) {
    diag[n] = td * rnp * rnt * SCALE;  // exact fp32 diagonal, already scaled
    sumexp[n] = 0.0f;
  }
}

// -------- Kernel B: 256x256-tile, 4-phase, SINGLE-buffered (in-place region staging),
//          swizzled-LDS bf16 MFMA NT-GEMM fused with sum-of-exp row reduction.
//          68 KB LDS -> 2 blocks/CU so independent blocks overlap read/MFMA sections.
__device__ __forceinline__ void load_lds16(const void* gsrc, void* ldst) {
  __builtin_amdgcn_global_load_lds(
      (const __attribute__((address_space(1))) void*)gsrc,
      (__attribute__((address_space(3))) void*)ldst, 16, 0, 0);
}

#define SBAR() __builtin_amdgcn_s_barrier()
#define WAIT_LGKM0() asm volatile("s_waitcnt lgkmcnt(0)" ::: "memory")
#define WAIT_LGKM8() asm volatile("s_waitcnt lgkmcnt(8)" ::: "memory")
#define WAIT_VM0() asm volatile("s_waitcnt vmcnt(0)" ::: "memory")

#define MFMA_QUAD(AF, MOFF, BF, NOFF)                                          \
  _Pragma("unroll") for (int m_ = 0; m_ < 4; ++m_)                             \
  _Pragma("unroll") for (int n_ = 0; n_ < 2; ++n_)                             \
  _Pragma("unroll") for (int k_ = 0; k_ < 2; ++k_)                             \
    acc[m_ + MOFF][n_ + NOFF] = __builtin_amdgcn_mfma_f32_16x16x32_bf16(       \
        AF[m_][k_], BF[n_][k_], acc[m_ + MOFF][n_ + NOFF], 0, 0, 0);

__global__ __launch_bounds__(512, 4) void cossim_gemm_lse(
    const __hip_bfloat16* __restrict__ P, const __hip_bfloat16* __restrict__ T,
    float* __restrict__ sumexp) {
  // [A=0/B=1][row 0..255][col 0..63] = 64 KiB, single-buffered (in-place staging)
  __shared__ __hip_bfloat16 lds[2][256][64];
  __shared__ float lds_rs[2][4][128];

  const int tid  = threadIdx.x;
  const int lane = tid & 63;
  const int w    = tid >> 6;   // 0..7
  const int wr   = w >> 2;     // wave row 0..1 (owns 128 C-rows)
  const int wc   = w & 3;      // wave col 0..3 (owns 64 C-cols)

  // L2-locality supertile swizzle (bijective on 1024 blocks = 32x32 tiles):
  //   xcd = bid&7 owns a fixed 8-tile-row x 16-tile-col region; its 4 sequential
  //   32-block rounds are 4x8 supertiles (A 1MB + B 2MB = 3MB < 4MB per-XCD L2).
  const int xcd  = blockIdx.x & 7;
  const int slot = blockIdx.x >> 3;       // 0..127: sequential per-XCD slot
  const int q    = slot >> 5;             // 0..3: which 4x8 supertile (round)
  const int u    = slot & 31;             // 0..31: position within supertile
  const int by   = (xcd >> 1) * 8 + (q >> 1) * 4 + (u >> 3);  // tile row 0..31
  const int bx   = (xcd & 1) * 16 + (q & 1) * 8 + (u & 7);    // tile col 0..31
  const int brow = by * 256;
  const int bcol = bx * 256;

  const __hip_bfloat16* gA = P + (size_t)brow * C_DIM;
  const __hip_bfloat16* gB = T + (size_t)bcol * C_DIM;

  // Stage one half-tile (128 rows x 64 cols) of A or B for K-tile t.
  // LDS dest is LINEAR (global_load_lds: wave-uniform base + lane*16); the bank-conflict
  // swizzle (chunk ^= row&7, 16B chunks) is applied by permuting the per-lane GLOBAL source.
  auto stage = [&](const __hip_bfloat16* gbase, int ab, int t, int h) {
    #pragma unroll
    for (int c = 0; c < 2; ++c) {
      const int rr  = (w * 2 + c) * 8 + (lane >> 3);          // row within half
      const int gch = (lane & 7) ^ ((lane >> 3) & 7);         // pre-swizzled source chunk
      const __hip_bfloat16* src =
          gbase + (size_t)(h * 128 + rr) * C_DIM + t * 64 + gch * 8;
      load_lds16(src, &lds[ab][h * 128 + (w * 2 + c) * 8][0]);
    }
  };

  const int arow0 = wr * 128 + (lane & 15);
  const int brow0 = wc * 64 + (lane & 15);
  const int chx   = lane >> 4;   // k-chunk within 32-slice
  const int swz   = lane & 7;    // == row & 7 for all fragment rows

  auto LDA = [&](int mm, int kk) -> bf16x8 {
    return *(const bf16x8*)&lds[0][arow0 + mm * 16][((kk * 4 + chx) ^ swz) * 8];
  };
  auto LDB = [&](int nn, int kk) -> bf16x8 {
    return *(const bf16x8*)&lds[1][brow0 + nn * 16][((kk * 4 + chx) ^ swz) * 8];
  };

  f32x4 acc[8][4] = {};

  // ---- prologue: stage tile0 fully; drain; barrier
  stage(gB, 1, 0, 0);
  stage(gB, 1, 0, 1);
  stage(gA, 0, 0, 0);
  stage(gA, 0, 0, 1);
  WAIT_VM0();
  SBAR();

  // ---- main loop: 4 phases per K-tile, in-place staging by region liveness
  #pragma unroll 2
  for (int s = 0; s < NT; ++s) {
    bf16x8 a03[4][2], a47[4][2], b01[2][2], b23[2][2];

    // phase 0: read A[m0-3], B[n0-1] (12 ds_read); MFMA m0-3 x n0-1
    #pragma unroll
    for (int m = 0; m < 4; ++m)
      #pragma unroll
      for (int kk = 0; kk < 2; ++kk) a03[m][kk] = LDA(m, kk);
    #pragma unroll
    for (int n = 0; n < 2; ++n)
      #pragma unroll
      for (int kk = 0; kk < 2; ++kk) b01[n][kk] = LDB(n, kk);
    WAIT_LGKM8();
    SBAR();
    WAIT_LGKM0();
    __builtin_amdgcn_s_setprio(1);
    MFMA_QUAD(a03, 0, b01, 0);
    __builtin_amdgcn_s_setprio(0);
    SBAR();

    // phase 1: read B[n2-3] (4); MFMA m0-3 x n2-3.  [B region dead after these reads]
    #pragma unroll
    for (int n = 0; n < 2; ++n)
      #pragma unroll
      for (int kk = 0; kk < 2; ++kk) b23[n][kk] = LDB(n + 2, kk);
    SBAR();
    WAIT_LGKM0();
    __builtin_amdgcn_s_setprio(1);
    MFMA_QUAD(a03, 0, b23, 2);
    __builtin_amdgcn_s_setprio(0);
    SBAR();

    // phase 2: read A[m4-7] (8); stage B(s+1) into dead B region; MFMA m4-7 x n2-3
    //          (all waves' B reads completed before phase-1's terminal barrier)
    #pragma unroll
    for (int m = 0; m < 4; ++m)
      #pragma unroll
      for (int kk = 0; kk < 2; ++kk) a47[m][kk] = LDA(m + 4, kk);
    if (s + 1 < NT) { stage(gB, 1, s + 1, 0); stage(gB, 1, s + 1, 1); }
    SBAR();
    WAIT_LGKM0();
    __builtin_amdgcn_s_setprio(1);
    MFMA_QUAD(a47, 4, b23, 2);
    __builtin_amdgcn_s_setprio(0);
    SBAR();

    // phase 3: stage A(s+1) into dead A region; MFMA m4-7 x n0-1; drain; barrier
    if (s + 1 < NT) { stage(gA, 0, s + 1, 0); stage(gA, 0, s + 1, 1); }
    SBAR();
    __builtin_amdgcn_s_setprio(1);
    MFMA_QUAD(a47, 4, b01, 0);
    __builtin_amdgcn_s_setprio(0);
    WAIT_VM0();
    SBAR();
  }

  // ---- epilogue: exp + row-sum. C/D: col = lane&15, row = (lane>>4)*4 + reg
  #pragma unroll
  for (int m = 0; m < 8; ++m) {
    #pragma unroll
    for (int r = 0; r < 4; ++r) {
      float v = exp2f(acc[m][0][r] * S2LOG) + exp2f(acc[m][1][r] * S2LOG) +
                exp2f(acc[m][2][r] * S2LOG) + exp2f(acc[m][3][r] * S2LOG);
      v += __shfl_xor(v, 1);
      v += __shfl_xor(v, 2);
      v += __shfl_xor(v, 4);
      v += __shfl_xor(v, 8);
      if ((lane & 15) == 0) lds_rs[wr][wc][m * 16 + (lane >> 4) * 4 + r] = v;
    }
  }
  __syncthreads();
  if (tid < 256) {
    const int rw = tid >> 7, ri = tid & 127;
    const float t = lds_rs[rw][0][ri] + lds_rs[rw][1][ri] +
                    lds_rs[rw][2][ri] + lds_rs[rw][3][ri];
    atomicAdd(&sumexp[brow + rw * 128 + ri], t);
  }
}

// -------- Kernel C: loss = mean(log(sumexp) - diag), 1024 threads, float4 loads
__global__ __launch_bounds__(1024) void cossim_loss(
    const float* __restrict__ sumexp, const float* __restrict__ diag,
    float* __restrict__ out, int N) {
  const int tid = threadIdx.x;
  const float4* s4 = (const float4*)sumexp;
  const float4* d4 = (const float4*)diag;
  float s = 0.0f;
  for (int i = tid; i < N / 4; i += 1024) {
    float4 a = s4[i];
    float4 b = d4[i];
    s += (logf(a.x) - b.x) + (logf(a.y) - b.y) + (logf(a.z) - b.z) + (logf(a.w) - b.w);
  }
  #pragma unroll
  for (int off = 32; off > 0; off >>= 1) s += __shfl_down(s, off);
  __shared__ float red[16];
  if ((tid & 63) == 0) red[tid >> 6] = s;
  __syncthreads();
  if (tid == 0) {
    float t = 0.0f;
    #pragma unroll
    for (int i = 0; i < 16; ++i) t += red[i];
    out[0] = t / (float)N;
  }
}

extern "C" void kernel_launch(void* const* d_in, const int* in_sizes, int n_in,
                              void* d_out, int out_size, void* d_ws, size_t ws_size,
                              hipStream_t stream) {
  const int C = C_DIM;
  const int N = in_sizes[0] / C;  // 8192
  const float* pred   = (const float*)d_in[0];
  const float* target = (const float*)d_in[1];
  float* out = (float*)d_out;

  char* ws = (char*)d_ws;
  __hip_bfloat16* pbf = (__hip_bfloat16*)ws;
  __hip_bfloat16* tbf = (__hip_bfloat16*)(ws + (size_t)N * C * 2);
  float* diag   = (float*)(ws + (size_t)N * C * 4);
  float* sumexp = diag + N;

  cossim_normalize<<<N, 128, 0, stream>>>(pred, target, pbf, tbf, diag, sumexp);
  const int nblk = (N / 256) * (N / 256);  // 1024
  cossim_gemm_lse<<<nblk, 512, 0, stream>>>(pbf, tbf, sumexp);
  cossim_loss<<<1, 1024, 0, stream>>>(sumexp, diag, out, N);
}

// Round 7
// 102.409 us; speedup vs baseline: 5.8556x; 5.8556x over previous
//
#include <hip/hip_runtime.h>
#include <hip/hip_bf16.h>

typedef __attribute__((ext_vector_type(4))) float f32x4;
typedef __attribute__((ext_vector_type(8))) short bf16x8;

#define C_DIM 512
#define SCALE 1.6487212707001282f            // exp(0.5)
#define S2LOG (SCALE * 1.4426950408889634f)  // exp(0.5) * log2(e)
#define NT 8                                  // C_DIM / 64 K-tiles

// -------- Kernel A: L2-normalize rows of pred/target -> bf16; exact fp32 diag; zero sumexp
__global__ __launch_bounds__(128) void cossim_normalize(
    const float* __restrict__ pred, const float* __restrict__ target,
    __hip_bfloat16* __restrict__ pbf, __hip_bfloat16* __restrict__ tbf,
    float* __restrict__ diag, float* __restrict__ sumexp) {
  const int n = blockIdx.x;
  const int t = threadIdx.x;  // 128 threads, 4 floats each = 512
  const float4* p4 = (const float4*)(pred + (size_t)n * C_DIM);
  const float4* q4 = (const float4*)(target + (size_t)n * C_DIM);
  float4 a = p4[t];
  float4 b = q4[t];
  float ssp = a.x*a.x + a.y*a.y + a.z*a.z + a.w*a.w;
  float sst = b.x*b.x + b.y*b.y + b.z*b.z + b.w*b.w;
  float dt  = a.x*b.x + a.y*b.y + a.z*b.z + a.w*b.w;
  #pragma unroll
  for (int off = 32; off > 0; off >>= 1) {
    ssp += __shfl_down(ssp, off);
    sst += __shfl_down(sst, off);
    dt  += __shfl_down(dt,  off);
  }
  __shared__ float red[3][2];
  const int wid = t >> 6;
  if ((t & 63) == 0) { red[0][wid] = ssp; red[1][wid] = sst; red[2][wid] = dt; }
  __syncthreads();
  const float tp = red[0][0] + red[0][1];
  const float tt = red[1][0] + red[1][1];
  const float td = red[2][0] + red[2][1];
  const float rnp = 1.0f / fmaxf(sqrtf(tp), 1e-12f);
  const float rnt = 1.0f / fmaxf(sqrtf(tt), 1e-12f);

  __hip_bfloat16 po[4], to[4];
  po[0] = __float2bfloat16(a.x * rnp); po[1] = __float2bfloat16(a.y * rnp);
  po[2] = __float2bfloat16(a.z * rnp); po[3] = __float2bfloat16(a.w * rnp);
  to[0] = __float2bfloat16(b.x * rnt); to[1] = __float2bfloat16(b.y * rnt);
  to[2] = __float2bfloat16(b.z * rnt); to[3] = __float2bfloat16(b.w * rnt);
  *(uint2*)(pbf + (size_t)n * C_DIM + t * 4) = *(const uint2*)po;
  *(uint2*)(tbf + (size_t)n * C_DIM + t * 4) = *(const uint2*)to;

  if (t == 0) {
    diag[n] = td * rnp * rnt * SCALE;  // exact fp32 diagonal, already scaled
    sumexp[n] = 0.0f;
  }
}

// -------- Kernel B: 256x128-tile, 256-thread, single-buffered in-place staging,
//          2 blocks/CU for cross-block pipe overlap. Swizzled-LDS bf16 MFMA NT-GEMM
//          fused with sum-of-exp row reduction.
__device__ __forceinline__ void load_lds16(const void* gsrc, void* ldst) {
  __builtin_amdgcn_global_load_lds(
      (const __attribute__((address_space(1))) void*)gsrc,
      (__attribute__((address_space(3))) void*)ldst, 16, 0, 0);
}

#define SBAR() __builtin_amdgcn_s_barrier()
#define WAIT_LGKM0() asm volatile("s_waitcnt lgkmcnt(0)" ::: "memory")
#define WAIT_LGKM8() asm volatile("s_waitcnt lgkmcnt(8)" ::: "memory")
#define WAIT_VM0() asm volatile("s_waitcnt vmcnt(0)" ::: "memory")

__global__ __launch_bounds__(256, 2) void cossim_gemm_lse(
    const __hip_bfloat16* __restrict__ P, const __hip_bfloat16* __restrict__ T,
    float* __restrict__ sumexp) {
  // Single-buffered tiles (in-place restage by liveness): A 32KB + B 16KB + rs 2KB = 50KB
  __shared__ __hip_bfloat16 ldsA[256][64];
  __shared__ __hip_bfloat16 ldsB[128][64];
  __shared__ float lds_rs[2][2][128];

  const int tid  = threadIdx.x;
  const int lane = tid & 63;
  const int w    = tid >> 6;   // 0..3
  const int wr   = w >> 1;     // wave row 0..1 (owns 128 C-rows)
  const int wc   = w & 1;      // wave col 0..1 (owns 64 C-cols)

  // L2-locality supertile swizzle, bijective on 2048 blocks = 32by x 64bx tiles.
  // Each XCD owns a 16by x 16bx region; its 4 sequential 64-block rounds are 8x8
  // supertiles: concurrent set = A 8*256 rows (2MB) + B 8*128 rows (1MB) < 4MB L2.
  const int xcd  = blockIdx.x & 7;
  const int slot = blockIdx.x >> 3;       // 0..255
  const int q    = slot >> 6;             // 0..3: round
  const int v    = slot & 63;             // 0..63: position in 8x8 supertile
  const int by   = (xcd >> 2) * 16 + (q >> 1) * 8 + (v >> 3);  // 0..31
  const int bx   = (xcd & 3) * 16 + (q & 1) * 8 + (v & 7);     // 0..63
  const int brow = by * 256;
  const int bcol = bx * 128;

  const __hip_bfloat16* gA = P + (size_t)brow * C_DIM;
  const __hip_bfloat16* gB = T + (size_t)bcol * C_DIM;

  // Stage K-tile t. LDS dest LINEAR (global_load_lds = uniform base + lane*16);
  // bank-conflict swizzle (chunk ^= row&7) applied by permuting the GLOBAL source.
  auto stageA = [&](int t) {
    #pragma unroll
    for (int c = 0; c < 8; ++c) {
      const int rr  = (w * 8 + c) * 8 + (lane >> 3);
      const int gch = (lane & 7) ^ ((lane >> 3) & 7);
      load_lds16(gA + (size_t)rr * C_DIM + t * 64 + gch * 8, &ldsA[(w * 8 + c) * 8][0]);
    }
  };
  auto stageB = [&](int t) {
    #pragma unroll
    for (int c = 0; c < 4; ++c) {
      const int rr  = (w * 4 + c) * 8 + (lane >> 3);
      const int gch = (lane & 7) ^ ((lane >> 3) & 7);
      load_lds16(gB + (size_t)rr * C_DIM + t * 64 + gch * 8, &ldsB[(w * 4 + c) * 8][0]);
    }
  };

  const int arow0 = wr * 128 + (lane & 15);
  const int brow0 = wc * 64 + (lane & 15);
  const int chx   = lane >> 4;   // k-chunk within 32-slice
  const int swz   = lane & 7;    // == row & 7 for all fragment rows

  auto LDA = [&](int mm, int kk) -> bf16x8 {
    return *(const bf16x8*)&ldsA[arow0 + mm * 16][((kk * 4 + chx) ^ swz) * 8];
  };
  auto LDB = [&](int nn, int kk) -> bf16x8 {
    return *(const bf16x8*)&ldsB[brow0 + nn * 16][((kk * 4 + chx) ^ swz) * 8];
  };

  f32x4 acc[8][4] = {};

  // ---- prologue: stage tile 0; drain; barrier
  stageA(0);
  stageB(0);
  WAIT_VM0();
  SBAR();

  // ---- main loop: 2 barriers per K-tile; waves/blocks free-run between them
  for (int s = 0; s < NT; ++s) {
    bf16x8 a03[4][2], a47[4][2], bf[4][2];

    // read all fragments of tile s: a03(8), B(8), a47(8) = 24 x ds_read_b128
    #pragma unroll
    for (int m = 0; m < 4; ++m)
      #pragma unroll
      for (int kk = 0; kk < 2; ++kk) a03[m][kk] = LDA(m, kk);
    #pragma unroll
    for (int n = 0; n < 4; ++n)
      #pragma unroll
      for (int kk = 0; kk < 2; ++kk) bf[n][kk] = LDB(n, kk);
    #pragma unroll
    for (int m = 0; m < 4; ++m)
      #pragma unroll
      for (int kk = 0; kk < 2; ++kk) a47[m][kk] = LDA(m + 4, kk);

    WAIT_LGKM8();  // a03 + B retired; a47 still in flight under MFMA below
    __builtin_amdgcn_s_setprio(1);
    #pragma unroll
    for (int m = 0; m < 4; ++m)
      #pragma unroll
      for (int n = 0; n < 4; ++n)
        #pragma unroll
        for (int kk = 0; kk < 2; ++kk)
          acc[m][n] = __builtin_amdgcn_mfma_f32_16x16x32_bf16(a03[m][kk], bf[n][kk], acc[m][n], 0, 0, 0);
    __builtin_amdgcn_s_setprio(0);

    WAIT_LGKM0();  // own reads of tile s fully retired
    SBAR();        // => ALL waves' reads retired: in-place restage is safe

    if (s + 1 < NT) { stageA(s + 1); stageB(s + 1); }  // 12 global_load_lds

    __builtin_amdgcn_s_setprio(1);
    #pragma unroll
    for (int m = 0; m < 4; ++m)
      #pragma unroll
      for (int n = 0; n < 4; ++n)
        #pragma unroll
        for (int kk = 0; kk < 2; ++kk)
          acc[m + 4][n] = __builtin_amdgcn_mfma_f32_16x16x32_bf16(a47[m][kk], bf[n][kk], acc[m + 4][n], 0, 0, 0);
    __builtin_amdgcn_s_setprio(0);

    WAIT_VM0();    // stage writes landed (covered by the 32 MFMAs above)
    SBAR();        // staged tile visible to all waves
  }

  // ---- epilogue: exp + row-sum. C/D: col = lane&15, row = (lane>>4)*4 + reg
  #pragma unroll
  for (int m = 0; m < 8; ++m) {
    #pragma unroll
    for (int r = 0; r < 4; ++r) {
      float vsum = exp2f(acc[m][0][r] * S2LOG) + exp2f(acc[m][1][r] * S2LOG) +
                   exp2f(acc[m][2][r] * S2LOG) + exp2f(acc[m][3][r] * S2LOG);
      vsum += __shfl_xor(vsum, 1);
      vsum += __shfl_xor(vsum, 2);
      vsum += __shfl_xor(vsum, 4);
      vsum += __shfl_xor(vsum, 8);
      if ((lane & 15) == 0) lds_rs[wr][wc][m * 16 + (lane >> 4) * 4 + r] = vsum;
    }
  }
  __syncthreads();
  {
    const int rw = tid >> 7, ri = tid & 127;
    const float t = lds_rs[rw][0][ri] + lds_rs[rw][1][ri];
    atomicAdd(&sumexp[brow + rw * 128 + ri], t);
  }
}

// -------- Kernel C: loss = mean(log(sumexp) - diag), 1024 threads, float4 loads
__global__ __launch_bounds__(1024) void cossim_loss(
    const float* __restrict__ sumexp, const float* __restrict__ diag,
    float* __restrict__ out, int N) {
  const int tid = threadIdx.x;
  const float4* s4 = (const float4*)sumexp;
  const float4* d4 = (const float4*)diag;
  float s = 0.0f;
  for (int i = tid; i < N / 4; i += 1024) {
    float4 a = s4[i];
    float4 b = d4[i];
    s += (logf(a.x) - b.x) + (logf(a.y) - b.y) + (logf(a.z) - b.z) + (logf(a.w) - b.w);
  }
  #pragma unroll
  for (int off = 32; off > 0; off >>= 1) s += __shfl_down(s, off);
  __shared__ float red[16];
  if ((tid & 63) == 0) red[tid >> 6] = s;
  __syncthreads();
  if (tid == 0) {
    float t = 0.0f;
    #pragma unroll
    for (int i = 0; i < 16; ++i) t += red[i];
    out[0] = t / (float)N;
  }
}

extern "C" void kernel_launch(void* const* d_in, const int* in_sizes, int n_in,
                              void* d_out, int out_size, void* d_ws, size_t ws_size,
                              hipStream_t stream) {
  const int C = C_DIM;
  const int N = in_sizes[0] / C;  // 8192
  const float* pred   = (const float*)d_in[0];
  const float* target = (const float*)d_in[1];
  float* out = (float*)d_out;

  char* ws = (char*)d_ws;
  __hip_bfloat16* pbf = (__hip_bfloat16*)ws;
  __hip_bfloat16* tbf = (__hip_bfloat16*)(ws + (size_t)N * C * 2);
  float* diag   = (float*)(ws + (size_t)N * C * 4);
  float* sumexp = diag + N;

  cossim_normalize<<<N, 128, 0, stream>>>(pred, target, pbf, tbf, diag, sumexp);
  const int nblk = (N / 256) * (N / 128);  // 2048
  cossim_gemm_lse<<<nblk, 256, 0, stream>>>(pbf, tbf, sumexp);
  cossim_loss<<<1, 1024, 0, stream>>>(sumexp, diag, out, N);
}